// Round 9
// baseline (446.342 us; speedup 1.0000x reference)
//
#include <hip/hip_runtime.h>
#include <hip/hip_bf16.h>
#include <stdint.h>

#define NB 512
#define NL 128
#define ND 512

typedef __bf16 bf16;
typedef __bf16 bf16x8 __attribute__((ext_vector_type(8)));
typedef float  f32x4  __attribute__((ext_vector_type(4)));

#define GLDS(src, dst) __builtin_amdgcn_global_load_lds( \
    (const __attribute__((address_space(1))) void*)(src), \
    (__attribute__((address_space(3))) void*)(dst), 16, 0, 0)

// ------- K1: gather embed rows -> bf16 + partial sumsq; y==2: att^T ------
// grid (NB, 3, 8), 256 thr. Dedicated high-occupancy BW kernel (R7: ~68us,
// near floor). Table reads nontemporal so they don't evict Ab/Bb from L3.
__global__ __launch_bounds__(256) void k_gather(const int* __restrict__ ctx1,
                                                const int* __restrict__ ctx2,
                                                const float* __restrict__ table,
                                                bf16* __restrict__ d1,
                                                bf16* __restrict__ d2,
                                                float* __restrict__ ss,
                                                const float* __restrict__ att,
                                                bf16* __restrict__ attT) {
    const int b = blockIdx.x, side = blockIdx.y, zc = blockIdx.z, t = threadIdx.x;
    if (side == 2) {                      // att transpose slice
        int chunk = b * 8 + zc;
        if (chunk < 1024) {
            int i = chunk * 256 + t;      // over 512*512
            int n = i >> 9, k = i & 511;
            attT[i] = (bf16)att[k * 512 + n];
        }
        return;
    }
    const int* __restrict__ ctx = side ? ctx2 : ctx1;
    bf16* __restrict__ dst = side ? d2 : d1;
    const int base = b * NL;
    const int dv = t & 127, lr = t >> 7;
    int idxs[8];
    #pragma unroll
    for (int i = 0; i < 8; ++i) idxs[i] = ctx[base + zc * 16 + i * 2 + lr];
    float acc = 0.f;
    #pragma unroll
    for (int i = 0; i < 8; ++i) {
        int l = zc * 16 + i * 2 + lr;
        f32x4 v = __builtin_nontemporal_load(
            (const f32x4*)table + (size_t)idxs[i] * (ND / 4) + dv);
        acc += v[0]*v[0] + v[1]*v[1] + v[2]*v[2] + v[3]*v[3];
        union { bf16 h[4]; uint2 u; } pk;
        pk.h[0] = (bf16)v[0]; pk.h[1] = (bf16)v[1];
        pk.h[2] = (bf16)v[2]; pk.h[3] = (bf16)v[3];
        *((uint2*)(dst + (size_t)(base + l) * ND) + dv) = pk.u;
    }
    for (int o = 32; o; o >>= 1) acc += __shfl_xor(acc, o);
    __shared__ float red[4];
    if ((t & 63) == 0) red[t >> 6] = acc;
    __syncthreads();
    if (t == 0) atomicAdd(&ss[side * NB + b], red[0] + red[1] + red[2] + red[3]);
}

// ---- MEGA3: R5's 68KB nc-chunked structure (2 blocks/CU, occ ~45%) +
//      R6/R7 mechanics (counted vmcnt, conflict-free stage swizzle,
//      setprio), reading L3-hot Ab/Bb (gather split out).
//  per nc in 0..3 (128-wide n-chunk):
//    ph1: Tchunk = A @ attT[nc]^T, 16 BK=32 dbuf steps, vmcnt(2)
//    tail: stage B-slice into dead stage bufs || write Tchunk->LDS (swz)
//    ph2: accS += Tchunk @ Bslice^T (4 k-32 substeps, regs persist)
//  then: tanh/S-store/sums/softmax; newA/newB via Ab/Bb re-read (L3-hot).
//  LDS 69888: stages 4x8K @0 | Tch 32K @32K | smalls @64K; pA/pB alias @0.
__global__ __launch_bounds__(512, 4) void k_mega3(
        const bf16* __restrict__ Ab, const bf16* __restrict__ attT,
        const bf16* __restrict__ Bb, float* __restrict__ Sout,
        const float* __restrict__ ss, const float* __restrict__ w_pred,
        const float* __restrict__ b_pred, float* __restrict__ logits) {
    const int b = blockIdx.x, row0 = b * NL, tid = threadIdx.x;
    const int lane = tid & 63, w = tid >> 6;
    const int lm = lane & 15, quad = lane >> 4;
    const int wm = (w & 1) * 64;              // m-half
    const int wn = (w >> 1) * 32;             // n-quarter within 128-chunk

    __shared__ __align__(16) char smem[69888];
    // stage arena @0 (32K): parity p -> A@p*16K, N@p*16K+8K; B sub-tiles i*8K
    bf16* Tch = (bf16*)(smem + 32768);        // [2ks][128][64] swz, 32K
    float* pA   = (float*)smem;               // final [8][512]
    float* pB   = (float*)(smem + 16384);     // final [8][512]
    float* red2 = (float*)(smem + 65600);     // [8]
    float* rowb = (float*)(smem + 65664);     // [4][128]
    float* colb = (float*)(smem + 67712);     // [2][128]
    float* wrow = (float*)(smem + 68736);     // [128]
    float* wcol = (float*)(smem + 69248);     // [128]

    const int rT = tid >> 2, slT = tid & 3;          // stage decomposition
    const int csT = slT ^ ((rT >> 1) & 3);           // pre-swizzled 16B slot

    f32x4 accS[4][2] = {};                    // S[wm..][wn..] persists

    for (int nc = 0; nc < 4; ++nc) {
        const bf16* attN = attT + (size_t)(nc * 128) * ND;
        f32x4 acc1[4][2] = {};                // Tchunk accumulator

        // prologue: stage k-step 0 into parity-0 bufs
        GLDS(Ab + (size_t)(row0 + rT) * ND + csT * 8, (bf16*)smem + tid * 8);
        GLDS(attN + (size_t)rT * ND + csT * 8, (bf16*)(smem + 8192) + tid * 8);

        for (int t = 0; t < 16; ++t) {
            if (t < 15) {
                const int k0 = (t + 1) * 32, p = (t + 1) & 1;
                GLDS(Ab + (size_t)(row0 + rT) * ND + k0 + csT * 8,
                     (bf16*)(smem + p * 16384) + tid * 8);
                GLDS(attN + (size_t)rT * ND + k0 + csT * 8,
                     (bf16*)(smem + p * 16384 + 8192) + tid * 8);
                asm volatile("s_waitcnt vmcnt(2)" ::: "memory");
            } else {
                asm volatile("s_waitcnt vmcnt(0)" ::: "memory");
            }
            __builtin_amdgcn_s_barrier();
            const bf16* A_ = (bf16*)(smem + (t & 1) * 16384);
            const bf16* N_ = (bf16*)(smem + (t & 1) * 16384 + 8192);
            bf16x8 af[4], bf2[2];
            #pragma unroll
            for (int t4 = 0; t4 < 4; ++t4) {
                int R = wm + t4 * 16 + lm;
                af[t4] = *(const bf16x8*)&A_[R * 32 + (quad ^ ((R >> 1) & 3)) * 8];
            }
            #pragma unroll
            for (int t2 = 0; t2 < 2; ++t2) {
                int R = wn + t2 * 16 + lm;
                bf2[t2] = *(const bf16x8*)&N_[R * 32 + (quad ^ ((R >> 1) & 3)) * 8];
            }
            __builtin_amdgcn_s_setprio(1);
            #pragma unroll
            for (int im = 0; im < 4; ++im)
                #pragma unroll
                for (int jn = 0; jn < 2; ++jn)
                    acc1[im][jn] = __builtin_amdgcn_mfma_f32_16x16x32_bf16(
                        af[im], bf2[jn], acc1[im][jn], 0, 0, 0);
            __builtin_amdgcn_s_setprio(0);
            __builtin_amdgcn_s_barrier();     // bufs reusable next iter
        }

        // ---- chunk tail: B-slice -> 4 dead stage bufs, Tchunk -> LDS ----
        #pragma unroll
        for (int i = 0; i < 4; ++i)
            GLDS(Bb + (size_t)(row0 + rT) * ND + nc * 128 + i * 32 + csT * 8,
                 (bf16*)(smem + i * 8192) + tid * 8);
        #pragma unroll
        for (int im = 0; im < 4; ++im)
        #pragma unroll
        for (int jn = 0; jn < 2; ++jn)
        #pragma unroll
        for (int p = 0; p < 4; ++p) {
            int m = wm + im * 16 + quad * 4 + p;   // C/D: col=lane&15, row=quad*4+reg
            int n = wn + jn * 16 + lm;             // 0..127 within chunk
            int ks = n >> 6, c = n & 63;
            int pos = (((c >> 3) ^ (m & 7)) << 3) + (c & 7);
            Tch[ks * 8192 + m * 64 + pos] = (bf16)acc1[im][jn][p];
        }
        __syncthreads();                      // B in LDS, Tch visible

        // ---- ph2: accS += Tchunk @ Bslice^T (k = this 128-wide slice) ----
        __builtin_amdgcn_s_setprio(1);
        #pragma unroll
        for (int th = 0; th < 2; ++th) {
            const bf16* Tk = Tch + th * 8192;
            #pragma unroll
            for (int kk = 0; kk < 2; ++kk) {
                const bf16* Bs_ = (bf16*)(smem + (th * 2 + kk) * 8192);
                const int ca = (kk * 4 + quad) ^ (lm & 7);
                bf16x8 af[4], bf2[2];
                #pragma unroll
                for (int t4 = 0; t4 < 4; ++t4)
                    af[t4] = *(const bf16x8*)&Tk[(wm + t4 * 16 + lm) * 64 + ca * 8];
                #pragma unroll
                for (int t2 = 0; t2 < 2; ++t2) {
                    int R = wn + t2 * 16 + lm;
                    bf2[t2] = *(const bf16x8*)&Bs_[R * 32 + (quad ^ ((R >> 1) & 3)) * 8];
                }
                #pragma unroll
                for (int im = 0; im < 4; ++im)
                    #pragma unroll
                    for (int jn = 0; jn < 2; ++jn)
                        accS[im][jn] = __builtin_amdgcn_mfma_f32_16x16x32_bf16(
                            af[im], bf2[jn], accS[im][jn], 0, 0, 0);
            }
        }
        __builtin_amdgcn_s_setprio(0);
        __syncthreads();                      // bufs dead before next prologue
    }

    // ---- S epilogue: tanh + store + row/col sums ----
    const float ssA = ss[b], ssB = ss[NB + b];
    const float sc = rsqrtf(ssA * ssB);
    float* __restrict__ Sb = Sout + (size_t)b * NL * NL;
    #pragma unroll
    for (int im = 0; im < 4; ++im)
    #pragma unroll
    for (int jn = 0; jn < 2; ++jn)
    #pragma unroll
    for (int p = 0; p < 4; ++p) {
        float v = tanhf(accS[im][jn][p] * sc);
        accS[im][jn][p] = v;
        int m = wm + im * 16 + quad * 4 + p;
        int n = wn + jn * 16 + lm;
        __builtin_nontemporal_store(v, &Sb[m * NL + n]);
    }
    #pragma unroll
    for (int im = 0; im < 4; ++im)
    #pragma unroll
    for (int p = 0; p < 4; ++p) {
        float r = accS[im][0][p] + accS[im][1][p];
        r += __shfl_xor(r, 1); r += __shfl_xor(r, 2);
        r += __shfl_xor(r, 4); r += __shfl_xor(r, 8);
        if (lm == 0) rowb[(w >> 1) * NL + wm + im * 16 + quad * 4 + p] = r;
    }
    #pragma unroll
    for (int jn = 0; jn < 2; ++jn) {
        float cv = 0.f;
        #pragma unroll
        for (int im = 0; im < 4; ++im)
            #pragma unroll
            for (int p = 0; p < 4; ++p) cv += accS[im][jn][p];
        cv += __shfl_xor(cv, 16); cv += __shfl_xor(cv, 32);
        if (quad == 0) colb[(w & 1) * NL + wn + jn * 16 + lm] = cv;
    }
    __syncthreads();

    // ---- softmax over means (wave0: rows, wave1: cols) ----
    if (tid < 64) {
        float a  = (rowb[tid] + rowb[NL + tid] + rowb[2 * NL + tid] + rowb[3 * NL + tid]) * (1.f / NL);
        float c2 = (rowb[tid + 64] + rowb[NL + tid + 64] + rowb[2 * NL + tid + 64] + rowb[3 * NL + tid + 64]) * (1.f / NL);
        float mx = fmaxf(a, c2);
        for (int o = 32; o; o >>= 1) mx = fmaxf(mx, __shfl_xor(mx, o));
        float e0 = expf(a - mx), e1 = expf(c2 - mx);
        float s = e0 + e1;
        for (int o = 32; o; o >>= 1) s += __shfl_xor(s, o);
        float inv = 1.f / s;
        wrow[tid] = e0 * inv; wrow[tid + 64] = e1 * inv;
    } else if (tid < 128) {
        int q = tid - 64;
        float a  = (colb[q] + colb[NL + q]) * (1.f / NL);
        float c2 = (colb[q + 64] + colb[NL + q + 64]) * (1.f / NL);
        float mx = fmaxf(a, c2);
        for (int o = 32; o; o >>= 1) mx = fmaxf(mx, __shfl_xor(mx, o));
        float e0 = expf(a - mx), e1 = expf(c2 - mx);
        float s = e0 + e1;
        for (int o = 32; o; o >>= 1) s += __shfl_xor(s, o);
        float inv = 1.f / s;
        wcol[q] = e0 * inv; wcol[q + 64] = e1 * inv;
    }
    __syncthreads();

    // ---- weighted sums of A/B rows (stage/Tch dead -> pA/pB; L3-hot) ----
    const int c = tid & 63, g = tid >> 6;
    const bf16* __restrict__ Abase = Ab + (size_t)b * NL * ND;
    const bf16* __restrict__ Bbase = Bb + (size_t)b * NL * ND;
    float aacc[8] = {}, bacc[8] = {};
    for (int l = g; l < NL; l += 8) {
        float wr = wrow[l], wc = wcol[l];
        bf16x8 va = *(const bf16x8*)(Abase + (size_t)l * ND + c * 8);
        bf16x8 vb = *(const bf16x8*)(Bbase + (size_t)l * ND + c * 8);
        #pragma unroll
        for (int j = 0; j < 8; ++j) {
            aacc[j] += wr * (float)va[j];
            bacc[j] += wc * (float)vb[j];
        }
    }
    #pragma unroll
    for (int j = 0; j < 8; ++j) {
        pA[g * ND + c * 8 + j] = aacc[j];
        pB[g * ND + c * 8 + j] = bacc[j];
    }
    __syncthreads();

    if (tid < 64) {
        float dot = 0.f;
        #pragma unroll
        for (int j = 0; j < 8; ++j) {
            int d = tid * 8 + j;
            float na = 0.f, nb = 0.f;
            #pragma unroll
            for (int g2 = 0; g2 < 8; ++g2) {
                na += pA[g2 * ND + d];
                nb += pB[g2 * ND + d];
            }
            dot += na * nb * w_pred[d];
        }
        for (int o = 32; o; o >>= 1) dot += __shfl_xor(dot, o);
        if (tid == 0)
            logits[b] = dot * rsqrtf(ssA) * rsqrtf(ssB) + b_pred[0];
    }
}

extern "C" void kernel_launch(void* const* d_in, const int* in_sizes, int n_in,
                              void* d_out, int out_size, void* d_ws, size_t ws_size,
                              hipStream_t stream) {
    const int*   t1c = (const int*)d_in[2];
    const int*   t2c = (const int*)d_in[3];
    const float* emb = (const float*)d_in[4];
    const float* att = (const float*)d_in[5];
    const float* wp  = (const float*)d_in[6];
    const float* bp  = (const float*)d_in[7];

    float* out    = (float*)d_out;
    float* logits = out;
    float* S      = out + NB;      // outputs: logits(512) then S(512*128*128)

    char* ws = (char*)d_ws;
    bf16*  Ab   = (bf16*)(ws);                              // 67,108,864 B
    bf16*  Bb   = (bf16*)(ws + 67108864);                   // 67,108,864 B
    bf16*  attT = (bf16*)(ws + 134217728);                  //    524,288 B
    float* ss   = (float*)(ws + 134742016);                 //      4,096 B

    hipMemsetAsync(ss, 0, 4096, stream);
    // dedicated BW kernel: gather (y=0,1) + att transpose (y=2)
    k_gather<<<dim3(NB, 3, 8), 256, 0, stream>>>(t1c, t2c, emb, Ab, Bb, ss, att, attT);
    // compute: 68KB LDS, 2 blocks/CU, nc-chunked T/S pipeline
    k_mega3<<<dim3(NB), 512, 0, stream>>>(Ab, attT, Bb, S, ss, wp, bp, logits);
}